// Round 9
// baseline (203.021 us; speedup 1.0000x reference)
//
#include <hip/hip_runtime.h>
#include <cstdint>
#include <cstddef>

#define E 32
#define Bsz 64
#define Lsz 2048
#define NCHUNK (Lsz / 64)

typedef float f32x4 __attribute__((ext_vector_type(4)));
typedef __bf16 bf16x8 __attribute__((ext_vector_type(8)));
typedef __bf16 bf16x4 __attribute__((ext_vector_type(4)));
typedef short s16x8 __attribute__((ext_vector_type(8)));
typedef short s16x4 __attribute__((ext_vector_type(4)));
typedef unsigned short u16;

typedef __attribute__((address_space(3))) unsigned int as3_u32;
typedef __attribute__((address_space(1))) const unsigned int as1_u32;

__device__ inline u16 f2bf(float f) {
    union { float f; unsigned u; } x; x.f = f;
    unsigned r = x.u + 0x7FFFu + ((x.u >> 16) & 1u);
    return (u16)(r >> 16);
}

__device__ inline float fexp2(float x) {
#if __has_builtin(__builtin_amdgcn_exp2f)
    return __builtin_amdgcn_exp2f(x);   // raw v_exp_f32
#else
    return exp2f(x);
#endif
}

// async global -> LDS, 16 B per lane; LDS dst is wave-uniform base (HW adds lane*16)
__device__ inline void glds(const void* g, void* l) {
    __builtin_amdgcn_global_load_lds((as1_u32*)g, (as3_u32*)l, 16, 0, 0);
}

// hardware transpose read: lane l elem r <- lds[base + (l&15)*2 + r*32 + (l>>4)*128]
#define TRR(dst, areg, imm) \
    asm volatile("ds_read_b64_tr_b16 %0, %1 offset:" #imm : "=v"(dst) : "v"(areg))

// PV mfma: D = A(16x16) * B(16x16) + C
__device__ inline f32x4 pv_mfma(bf16x4 a, bf16x4 b, f32x4 c) {
#if __has_builtin(__builtin_amdgcn_mfma_f32_16x16x16_bf16)
    return __builtin_amdgcn_mfma_f32_16x16x16_bf16(a, b, c, 0, 0, 0);
#elif __has_builtin(__builtin_amdgcn_mfma_f32_16x16x16bf16_1k)
    return __builtin_amdgcn_mfma_f32_16x16x16bf16_1k(
        __builtin_bit_cast(s16x4, a), __builtin_bit_cast(s16x4, b), c, 0, 0, 0);
#else
    asm volatile("s_nop 1\n\t"
                 "v_mfma_f32_16x16x16_bf16 %0, %1, %2, %0\n\t"
                 "s_nop 3"
                 : "+v"(c) : "v"(a), "v"(b));
    return c;
#endif
}

// ---------------- Full PSF mask: M[i][j] = bilinear(i,j) / sqrt(E) * log2(e), bf16 ----------------
// Computed ONCE; the per-batch row-lerp in the attn loop (64x redundant) is gone.
__global__ __launch_bounds__(256) void mask_kernel(u16* __restrict__ M) {
    int g = blockIdx.x * 256 + threadIdx.x;
    int i = g >> 11, j = g & 2047;
    float z = 0.f;
    #pragma unroll
    for (int x = -10; x <= 10; ++x) z += __expf(-0.125f * (float)(x * x));
    const float scale = 21.0f / 2048.0f;
    float si = fmaxf((i + 0.5f) * scale - 0.5f, 0.f);
    float sj = fmaxf((j + 0.5f) * scale - 0.5f, 0.f);
    int i0 = (int)si; float fi = si - (float)i0;
    int j0 = (int)sj; float fj = sj - (float)j0;
    int i0c = min(i0, 20), i1c = min(i0 + 1, 20);
    int j0c = min(j0, 20), j1c = min(j0 + 1, 20);
    int d00 = abs(i0c - j0c), d01 = abs(i0c - j1c), d10 = abs(i1c - j0c), d11 = abs(i1c - j1c);
    float t00 = __expf(-0.125f * (float)(d00 * d00));
    float t01 = __expf(-0.125f * (float)(d01 * d01));
    float t10 = __expf(-0.125f * (float)(d10 * d10));
    float t11 = __expf(-0.125f * (float)(d11 * d11));
    float m = (1.f - fi) * ((1.f - fj) * t00 + fj * t01)
            + fi * ((1.f - fj) * t10 + fj * t11);
    m = (m / z) * 0.17677669529663687f * 1.4426950408889634f;  // /sqrt(32)*log2(e)
    M[g] = f2bf(m);
}

// ---------------- QKV: x[B][E][L] f32 -> Q,K [B][L][E] bf16; V chunked tr-layout ----------------
// Vc[b][jc=l>>6][eh=e>>4][j=l&63][e&15]  (matches attn's LDS image; 4-KB chunks)
__global__ __launch_bounds__(256) void qkv_kernel(const float* __restrict__ x,
        const float* __restrict__ Wqkv, const float* __restrict__ bqkv,
        u16* __restrict__ Q, u16* __restrict__ K, u16* __restrict__ Vc) {
    int g = blockIdx.x * 256 + threadIdx.x;
    int b = g >> 11, l = g & 2047;
    float xr[E];
    #pragma unroll
    for (int c = 0; c < E; ++c) xr[c] = x[((size_t)b * E + c) * Lsz + l];

    #pragma unroll
    for (int part = 0; part < 2; ++part) {
        u16* dst = (part == 0) ? Q : K;
        s16x8 pk[4];
        #pragma unroll
        for (int e = 0; e < E; ++e) {
            int o = part * E + e;
            float acc = bqkv[o];
            #pragma unroll
            for (int c = 0; c < E; ++c) acc += xr[c] * Wqkv[o * E + c];
            pk[e >> 3][e & 7] = (short)f2bf(acc);
        }
        s16x8* dp = (s16x8*)(dst + ((size_t)b * Lsz + l) * E);
        #pragma unroll
        for (int q8 = 0; q8 < 4; ++q8) dp[q8] = pk[q8];
    }
    s16x8 pv[4];
    #pragma unroll
    for (int e = 0; e < E; ++e) {
        int o = 2 * E + e;
        float acc = bqkv[o];
        #pragma unroll
        for (int c = 0; c < E; ++c) acc += xr[c] * Wqkv[o * E + c];
        pv[e >> 3][e & 7] = (short)f2bf(acc);
    }
    u16* vd = Vc + ((size_t)b * 32 + (l >> 6)) * 2048 + (size_t)(l & 63) * 16;
    *(s16x8*)(vd)            = pv[0];   // eh=0, e 0..7
    *(s16x8*)(vd + 8)        = pv[1];   // eh=0, e 8..15
    *(s16x8*)(vd + 1024)     = pv[2];   // eh=1, e 16..23
    *(s16x8*)(vd + 1024 + 8) = pv[3];   // eh=1, e 24..31
}

// ---------------- Flash attention v6: LDS-staged chunks, tr-read V, precomputed M ----------------
// 1024 blocks (B x L/128), 4 waves x 32 q-rows. j-chunk 64, double-buffered LDS.
// XCD = blk % 8 = qblk % 8 -> all 64 batches sharing a qblk hit the same XCD:
// that XCD's M working set is 1 MB -> L2-resident mask reads.
__global__ __launch_bounds__(256, 4) void attn_kernel(const u16* __restrict__ Q,
        const u16* __restrict__ Kg, const u16* __restrict__ Vc,
        const u16* __restrict__ M, float* __restrict__ O) {
    int blk = blockIdx.x;
    int b = blk >> 4;
    int qblk = blk & 15;
    int tid = threadIdx.x;
    int lane = tid & 63;
    int lrow = lane & 15, kgrp = lane >> 4;
    int qbase = qblk * 128 + (tid >> 6) * 32;

    __shared__ __align__(1024) u16 K_lds[2][64][32];      // 8 KB, XOR-swizzled slots
    __shared__ __align__(2048) u16 V_lds[2][2][64][16];   // 8 KB, tr-read layout

    const size_t bLE = (size_t)b * Lsz * E;
    bf16x8 qf0 = *(const bf16x8*)(Q + bLE + (size_t)(qbase + lrow) * E + kgrp * 8);
    bf16x8 qf1 = *(const bf16x8*)(Q + bLE + (size_t)(qbase + 16 + lrow) * E + kgrp * 8);

    // precomputed mask rows for this lane's two q-rows
    const u16* mp0 = M + (size_t)(qbase + lrow) * Lsz + kgrp * 4;
    const u16* mp1 = mp0 + (size_t)16 * Lsz;

    // staging addresses. K source pre-swizzled so LDS slot s holds K[j][slot s^(j&3)]
    const char* kcbase = (const char*)(Kg + bLE);
    const char* vcbase = (const char*)(Vc + bLE);
    int j_of_tid = tid >> 2;
    int ksrc_off = j_of_tid * 64 + (((tid & 3) ^ (j_of_tid & 3)) << 4);
    int vsrc_off = tid * 16;
    u16* kdst = &K_lds[0][(tid >> 6) * 16][0];        // wave-uniform
    u16* vdst = &V_lds[0][0][0][0] + (tid >> 6) * 512;
    int kslot = (kgrp ^ (lrow & 3)) * 8;              // swizzled read slot (halfs)
    unsigned vtr0 = (unsigned)(uintptr_t)(__attribute__((address_space(3))) u16*)(&V_lds[0][0][0][0])
                  + (unsigned)(lane * 8);

#define STAGE(bufn, jc_) do { \
    glds(kcbase + (size_t)(jc_) * 4096 + ksrc_off, kdst + (bufn) * 2048); \
    glds(vcbase + (size_t)(jc_) * 4096 + vsrc_off, vdst + (bufn) * 2048); \
} while (0)

    f32x4 o00 = {0,0,0,0}, o01 = {0,0,0,0}, o10 = {0,0,0,0}, o11 = {0,0,0,0};
    f32x4 dn0 = {0,0,0,0}, dn1 = {0,0,0,0};
    bf16x4 ones = {(__bf16)1.0f, (__bf16)1.0f, (__bf16)1.0f, (__bf16)1.0f};

#define JT(jt, vr0, vr1) do { \
    bf16x8 kf = *(const bf16x8*)&K_lds[buf][(jt) * 16 + lrow][kslot]; \
    f32x4 zc = {0,0,0,0}; \
    f32x4 s0 = __builtin_amdgcn_mfma_f32_16x16x32_bf16(kf, qf0, zc, 0, 0, 0); \
    f32x4 s1 = __builtin_amdgcn_mfma_f32_16x16x32_bf16(kf, qf1, zc, 0, 0, 0); \
    bf16x4 mm0 = *(const bf16x4*)(mp0 + jco + (jt) * 16); \
    bf16x4 mm1 = *(const bf16x4*)(mp1 + jco + (jt) * 16); \
    bf16x4 pa0, pa1; \
    _Pragma("unroll") for (int r = 0; r < 4; ++r) \
        pa0[r] = (__bf16)fexp2(s0[r] * (float)mm0[r]); \
    _Pragma("unroll") for (int r = 0; r < 4; ++r) \
        pa1[r] = (__bf16)fexp2(s1[r] * (float)mm1[r]); \
    bf16x4 vf0 = __builtin_bit_cast(bf16x4, vr0); \
    bf16x4 vf1 = __builtin_bit_cast(bf16x4, vr1); \
    o00 = pv_mfma(pa0, vf0, o00); \
    o01 = pv_mfma(pa0, vf1, o01); \
    o10 = pv_mfma(pa1, vf0, o10); \
    o11 = pv_mfma(pa1, vf1, o11); \
    dn0 = pv_mfma(pa0, ones, dn0); \
    dn1 = pv_mfma(pa1, ones, dn1); \
} while (0)

    int buf = 0;
    STAGE(0, 0);
    __syncthreads();
    #pragma unroll 1
    for (int jc = 0; jc < NCHUNK; ++jc) {
        if (jc + 1 < NCHUNK) STAGE(buf ^ 1, jc + 1);   // issue next chunk (other buffer)
        unsigned av = vtr0 + (buf ? 4096u : 0u);
        s16x4 v00r, v01r, v10r, v11r, v20r, v21r, v30r, v31r;
        TRR(v00r, av, 0);    TRR(v01r, av, 2048);      // jt0: eh0, eh1
        TRR(v10r, av, 512);  TRR(v11r, av, 2560);      // jt1
        TRR(v20r, av, 1024); TRR(v21r, av, 3072);      // jt2
        TRR(v30r, av, 1536); TRR(v31r, av, 3584);      // jt3
        asm volatile("s_waitcnt lgkmcnt(0)" ::: "memory");
        __builtin_amdgcn_sched_barrier(0);
        const int jco = jc * 64;
        JT(0, v00r, v01r);
        JT(1, v10r, v11r);
        JT(2, v20r, v21r);
        JT(3, v30r, v31r);
        __syncthreads();   // drains stage vmcnt; all waves done reading buf
        buf ^= 1;
    }
#undef JT
#undef STAGE

    // epilogue: denom from ones-MFMA in matching layout -> no shuffles
    #pragma unroll
    for (int r = 0; r < 4; ++r) {
        float inv0 = 1.0f / dn0[r];
        float inv1 = 1.0f / dn1[r];
        size_t r0 = (size_t)(qbase + kgrp * 4 + r);
        size_t r1 = (size_t)(qbase + 16 + kgrp * 4 + r);
        O[bLE + r0 * E + lrow]      = o00[r] * inv0;
        O[bLE + r0 * E + 16 + lrow] = o01[r] * inv0;
        O[bLE + r1 * E + lrow]      = o10[r] * inv1;
        O[bLE + r1 * E + 16 + lrow] = o11[r] * inv1;
    }
}

// ---------------- Output projection: O[B][L][E] f32 -> y[B][E][L] f32 ----------------
__global__ __launch_bounds__(256) void oproj_kernel(const float* __restrict__ O,
        const float* __restrict__ Wout, const float* __restrict__ bout,
        float* __restrict__ y) {
    int g = blockIdx.x * 256 + threadIdx.x;
    int b = g >> 11, l = g & 2047;
    float orow[E];
    const float* src = O + ((size_t)b * Lsz + l) * E;
    #pragma unroll
    for (int e = 0; e < E; e += 4) {
        f32x4 t = *(const f32x4*)(src + e);
        orow[e] = t[0]; orow[e + 1] = t[1]; orow[e + 2] = t[2]; orow[e + 3] = t[3];
    }
    #pragma unroll
    for (int c = 0; c < E; ++c) {
        float acc = bout[c];
        #pragma unroll
        for (int e = 0; e < E; ++e) acc += orow[e] * Wout[c * E + e];
        y[((size_t)b * E + c) * Lsz + l] = acc;
    }
}

extern "C" void kernel_launch(void* const* d_in, const int* in_sizes, int n_in,
                              void* d_out, int out_size, void* d_ws, size_t ws_size,
                              hipStream_t stream) {
    const float* x    = (const float*)d_in[0];
    const float* Wqkv = (const float*)d_in[1];
    const float* bqkv = (const float*)d_in[2];
    const float* Wout = (const float*)d_in[3];
    const float* bout = (const float*)d_in[4];
    float* y = (float*)d_out;

    char* ws = (char*)d_ws;
    const size_t szQ = (size_t)Bsz * Lsz * E * sizeof(u16);   // 8.39 MB
    const size_t szM = (size_t)Lsz * Lsz * sizeof(u16);       // 8.39 MB
    u16* Q   = (u16*)(ws);
    u16* K   = (u16*)(ws + szQ);
    u16* Vc  = (u16*)(ws + 2 * szQ);
    u16* M   = (u16*)(ws + 3 * szQ);
    float* O = (float*)(ws + 3 * szQ + szM);                  // 16.78 MB f32

    hipLaunchKernelGGL(mask_kernel, dim3((Lsz * Lsz) / 256), dim3(256), 0, stream, M);
    hipLaunchKernelGGL(qkv_kernel, dim3((Bsz * Lsz) / 256), dim3(256), 0, stream,
                       x, Wqkv, bqkv, Q, K, Vc);
    hipLaunchKernelGGL(attn_kernel, dim3(Bsz * (Lsz / 128)), dim3(256), 0, stream,
                       Q, K, Vc, M, O);
    hipLaunchKernelGGL(oproj_kernel, dim3((Bsz * Lsz) / 256), dim3(256), 0, stream,
                       O, Wout, bout, y);
}

// Round 10
// 194.243 us; speedup vs baseline: 1.0452x; 1.0452x over previous
//
#include <hip/hip_runtime.h>
#include <cstdint>
#include <cstddef>

#define E 32
#define Bsz 64
#define Lsz 2048
#define JCHUNK 128
#define NCH (Lsz / JCHUNK)   // 16

typedef float f32x4 __attribute__((ext_vector_type(4)));
typedef __bf16 bf16x8 __attribute__((ext_vector_type(8)));
typedef __bf16 bf16x4 __attribute__((ext_vector_type(4)));
typedef short s16x8 __attribute__((ext_vector_type(8)));
typedef short s16x4 __attribute__((ext_vector_type(4)));
typedef unsigned short u16;

typedef __attribute__((address_space(3))) unsigned int as3_u32;
typedef __attribute__((address_space(1))) const unsigned int as1_u32;

__device__ inline u16 f2bf(float f) {
    union { float f; unsigned u; } x; x.f = f;
    unsigned r = x.u + 0x7FFFu + ((x.u >> 16) & 1u);
    return (u16)(r >> 16);
}

__device__ inline float fexp2(float x) {
#if __has_builtin(__builtin_amdgcn_exp2f)
    return __builtin_amdgcn_exp2f(x);   // raw v_exp_f32
#else
    return exp2f(x);
#endif
}

// async global -> LDS, 16 B per lane; LDS dst must be wave-uniform (HW adds lane*16)
__device__ inline void glds(const void* g, void* l) {
    __builtin_amdgcn_global_load_lds((as1_u32*)g, (as3_u32*)l, 16, 0, 0);
}

// hardware transpose read (validated v5/v6): 16x16 bf16 subtile -> B-fragment
#define TRR(dst, areg, imm) \
    asm volatile("ds_read_b64_tr_b16 %0, %1 offset:" #imm : "=v"(dst) : "v"(areg))

// PV mfma: D = A(16x16) * B(16x16) + C
__device__ inline f32x4 pv_mfma(bf16x4 a, bf16x4 b, f32x4 c) {
#if __has_builtin(__builtin_amdgcn_mfma_f32_16x16x16_bf16)
    return __builtin_amdgcn_mfma_f32_16x16x16_bf16(a, b, c, 0, 0, 0);
#elif __has_builtin(__builtin_amdgcn_mfma_f32_16x16x16bf16_1k)
    return __builtin_amdgcn_mfma_f32_16x16x16bf16_1k(
        __builtin_bit_cast(s16x4, a), __builtin_bit_cast(s16x4, b), c, 0, 0, 0);
#else
    asm volatile("s_nop 1\n\t"
                 "v_mfma_f32_16x16x16_bf16 %0, %1, %2, %0\n\t"
                 "s_nop 3"
                 : "+v"(c) : "v"(a), "v"(b));
    return c;
#endif
}

// ---------------- Full PSF mask: M[i][j] = bilinear(i,j) / sqrt(E) * log2(e), bf16 ----------------
// Z (template normalizer) hoisted to a compile-time constant: kills 21 exps/thread.
__global__ __launch_bounds__(256) void mask_kernel(u16* __restrict__ M) {
    int g = blockIdx.x * 256 + threadIdx.x;
    int i = g >> 11, j = g & 2047;
    const float scale = 21.0f / 2048.0f;
    float si = fmaxf((i + 0.5f) * scale - 0.5f, 0.f);
    float sj = fmaxf((j + 0.5f) * scale - 0.5f, 0.f);
    int i0 = (int)si; float fi = si - (float)i0;
    int j0 = (int)sj; float fj = sj - (float)j0;
    int i0c = min(i0, 20), i1c = min(i0 + 1, 20);
    int j0c = min(j0, 20), j1c = min(j0 + 1, 20);
    int d00 = abs(i0c - j0c), d01 = abs(i0c - j1c), d10 = abs(i1c - j0c), d11 = abs(i1c - j1c);
    float t00 = __expf(-0.125f * (float)(d00 * d00));
    float t01 = __expf(-0.125f * (float)(d01 * d01));
    float t10 = __expf(-0.125f * (float)(d10 * d10));
    float t11 = __expf(-0.125f * (float)(d11 * d11));
    float m = (1.f - fi) * ((1.f - fj) * t00 + fj * t01)
            + fi * ((1.f - fj) * t10 + fj * t11);
    // * 1/sqrt(32) * log2(e) / Z, all folded at compile time
    m = m * (0.17677669529663687f * 1.4426950408889634f / 5.0132563952f);
    M[g] = f2bf(m);
}

// ---------------- QKV: x[B][E][L] f32 -> Q,K [B][L][E] bf16; V chunked tr-layout ----------------
// Vc[b][jc=l>>7][eh=e>>4][j=l&127][e&15]  (8-KB chunks = attn's LDS image)
__global__ __launch_bounds__(256) void qkv_kernel(const float* __restrict__ x,
        const float* __restrict__ Wqkv, const float* __restrict__ bqkv,
        u16* __restrict__ Q, u16* __restrict__ K, u16* __restrict__ Vc) {
    int g = blockIdx.x * 256 + threadIdx.x;
    int b = g >> 11, l = g & 2047;
    float xr[E];
    #pragma unroll
    for (int c = 0; c < E; ++c) xr[c] = x[((size_t)b * E + c) * Lsz + l];

    #pragma unroll
    for (int part = 0; part < 2; ++part) {
        u16* dst = (part == 0) ? Q : K;
        s16x8 pk[4];
        #pragma unroll
        for (int e = 0; e < E; ++e) {
            int o = part * E + e;
            float acc = bqkv[o];
            #pragma unroll
            for (int c = 0; c < E; ++c) acc += xr[c] * Wqkv[o * E + c];
            pk[e >> 3][e & 7] = (short)f2bf(acc);
        }
        s16x8* dp = (s16x8*)(dst + ((size_t)b * Lsz + l) * E);
        #pragma unroll
        for (int q8 = 0; q8 < 4; ++q8) dp[q8] = pk[q8];
    }
    s16x8 pv[4];
    #pragma unroll
    for (int e = 0; e < E; ++e) {
        int o = 2 * E + e;
        float acc = bqkv[o];
        #pragma unroll
        for (int c = 0; c < E; ++c) acc += xr[c] * Wqkv[o * E + c];
        pv[e >> 3][e & 7] = (short)f2bf(acc);
    }
    u16* vd = Vc + ((size_t)b * 16 + (l >> 7)) * 4096 + (size_t)(l & 127) * 16;
    *(s16x8*)(vd)            = pv[0];   // eh=0, e 0..7
    *(s16x8*)(vd + 8)        = pv[1];   // eh=0, e 8..15
    *(s16x8*)(vd + 2048)     = pv[2];   // eh=1, e 16..23
    *(s16x8*)(vd + 2048 + 8) = pv[3];   // eh=1, e 24..31
}

// ---------------- Flash attention v7: 128-j chunks, LDS dbuf, tr-read V, setprio ----------------
// 1024 blocks (B x L/128), 4 waves x 32 q-rows. 16 chunks, 1 barrier each.
// LDS (dynamic, 32 KB): K[2][128][32]h at byte 0; V[2][2][128][16]h at byte 16384.
__global__ __launch_bounds__(256, 4) void attn_kernel(const u16* __restrict__ Q,
        const u16* __restrict__ Kg, const u16* __restrict__ Vc,
        const u16* __restrict__ M, float* __restrict__ O) {
    extern __shared__ char smem[];
    int blk = blockIdx.x;
    int b = blk >> 4;
    int qblk = blk & 15;
    int tid = threadIdx.x;
    int wave = tid >> 6, lane = tid & 63;
    int lrow = lane & 15, kgrp = lane >> 4;
    int qbase = qblk * 128 + wave * 32;

    const size_t bLE = (size_t)b * Lsz * E;
    bf16x8 qf0 = *(const bf16x8*)(Q + bLE + (size_t)(qbase + lrow) * E + kgrp * 8);
    bf16x8 qf1 = *(const bf16x8*)(Q + bLE + (size_t)(qbase + 16 + lrow) * E + kgrp * 8);

    const u16* mp0 = M + (size_t)(qbase + lrow) * Lsz + kgrp * 4;
    const u16* mp1 = mp0 + (size_t)16 * Lsz;

    // K staging: LDS[row][slot] holds K[row][slot ^ (row&3)] (16B slots)
    const char* kcbase = (const char*)(Kg + bLE);
    const char* vcbase = (const char*)(Vc + bLE);
    int s4 = tid & 3;
    int krow0 = wave * 32 + (lane >> 2);            // h=0 rows
    int krow1 = krow0 + 16;                          // h=1 rows
    int ksrc0 = krow0 * 64 + ((s4 ^ (krow0 & 3)) << 4);
    int ksrc1 = krow1 * 64 + ((s4 ^ (krow1 & 3)) << 4);
    int lane16 = lane * 16;
    u16* smem_h = (u16*)smem;
    int kslot = (kgrp ^ (lrow & 3)) * 8;             // swizzled read slot (halfs)
    unsigned vbase = (unsigned)(uintptr_t)(__attribute__((address_space(3))) u16*)(smem_h + 8192)
                   + (unsigned)(lane * 8);

#define STAGE(bufn, jc_) do { \
    const char* kc_ = kcbase + (size_t)(jc_) * 8192; \
    const char* vc_ = vcbase + (size_t)(jc_) * 8192; \
    glds(kc_ + ksrc0, smem + (bufn) * 8192 + wave * 2048); \
    glds(kc_ + ksrc1, smem + (bufn) * 8192 + wave * 2048 + 1024); \
    glds(vc_ + wave * 2048 + lane16,        smem + 16384 + (bufn) * 8192 + wave * 2048); \
    glds(vc_ + wave * 2048 + 1024 + lane16, smem + 16384 + (bufn) * 8192 + wave * 2048 + 1024); \
} while (0)

    f32x4 o00 = {0,0,0,0}, o01 = {0,0,0,0}, o10 = {0,0,0,0}, o11 = {0,0,0,0};
    f32x4 dn0 = {0,0,0,0}, dn1 = {0,0,0,0};
    bf16x4 ones = {(__bf16)1.0f, (__bf16)1.0f, (__bf16)1.0f, (__bf16)1.0f};

#define JT(jt, vr0, vr1) do { \
    bf16x8 kf = *(const bf16x8*)(smem_h + buf * 4096 + ((jt) * 16 + lrow) * 32 + kslot); \
    f32x4 zc = {0,0,0,0}; \
    f32x4 s0 = __builtin_amdgcn_mfma_f32_16x16x32_bf16(kf, qf0, zc, 0, 0, 0); \
    f32x4 s1 = __builtin_amdgcn_mfma_f32_16x16x32_bf16(kf, qf1, zc, 0, 0, 0); \
    bf16x4 mm0 = *(const bf16x4*)(mp0 + jco + (jt) * 16); \
    bf16x4 mm1 = *(const bf16x4*)(mp1 + jco + (jt) * 16); \
    bf16x4 pa0, pa1; \
    _Pragma("unroll") for (int r = 0; r < 4; ++r) \
        pa0[r] = (__bf16)fexp2(s0[r] * (float)mm0[r]); \
    _Pragma("unroll") for (int r = 0; r < 4; ++r) \
        pa1[r] = (__bf16)fexp2(s1[r] * (float)mm1[r]); \
    bf16x4 vf0 = __builtin_bit_cast(bf16x4, vr0); \
    bf16x4 vf1 = __builtin_bit_cast(bf16x4, vr1); \
    o00 = pv_mfma(pa0, vf0, o00); \
    o01 = pv_mfma(pa0, vf1, o01); \
    o10 = pv_mfma(pa1, vf0, o10); \
    o11 = pv_mfma(pa1, vf1, o11); \
    dn0 = pv_mfma(pa0, ones, dn0); \
    dn1 = pv_mfma(pa1, ones, dn1); \
} while (0)

    int buf = 0;
    STAGE(0, 0);
    __syncthreads();
    #pragma unroll 1
    for (int jc = 0; jc < NCH; ++jc) {
        if (jc + 1 < NCH) STAGE(buf ^ 1, jc + 1);    // next chunk into other buffer
        const int jco = jc * JCHUNK;
        unsigned av = vbase + (buf ? 8192u : 0u);
        s16x4 t00, t01, t10, t11, t20, t21, t30, t31;
        // batch A: jt 0..3 (eh0 at jt*512, eh1 at 4096+jt*512)
        TRR(t00, av, 0);    TRR(t01, av, 4096);
        TRR(t10, av, 512);  TRR(t11, av, 4608);
        TRR(t20, av, 1024); TRR(t21, av, 5120);
        TRR(t30, av, 1536); TRR(t31, av, 5632);
        asm volatile("s_waitcnt lgkmcnt(0)" ::: "memory");
        __builtin_amdgcn_sched_barrier(0);
        __builtin_amdgcn_s_setprio(1);
        JT(0, t00, t01);
        JT(1, t10, t11);
        JT(2, t20, t21);
        JT(3, t30, t31);
        __builtin_amdgcn_s_setprio(0);
        // batch B: jt 4..7
        TRR(t00, av, 2048); TRR(t01, av, 6144);
        TRR(t10, av, 2560); TRR(t11, av, 6656);
        TRR(t20, av, 3072); TRR(t21, av, 7168);
        TRR(t30, av, 3584); TRR(t31, av, 7680);
        asm volatile("s_waitcnt lgkmcnt(0)" ::: "memory");
        __builtin_amdgcn_sched_barrier(0);
        __builtin_amdgcn_s_setprio(1);
        JT(4, t00, t01);
        JT(5, t10, t11);
        JT(6, t20, t21);
        JT(7, t30, t31);
        __builtin_amdgcn_s_setprio(0);
        __syncthreads();   // stage loads landed during compute; drain is cheap
        buf ^= 1;
    }
#undef JT
#undef STAGE

    // epilogue: denom from ones-MFMA in matching layout -> no shuffles
    #pragma unroll
    for (int r = 0; r < 4; ++r) {
        float inv0 = 1.0f / dn0[r];
        float inv1 = 1.0f / dn1[r];
        size_t r0 = (size_t)(qbase + kgrp * 4 + r);
        size_t r1 = (size_t)(qbase + 16 + kgrp * 4 + r);
        O[bLE + r0 * E + lrow]      = o00[r] * inv0;
        O[bLE + r0 * E + 16 + lrow] = o01[r] * inv0;
        O[bLE + r1 * E + lrow]      = o10[r] * inv1;
        O[bLE + r1 * E + 16 + lrow] = o11[r] * inv1;
    }
}

// ---------------- Output projection: O[B][L][E] f32 -> y[B][E][L] f32 ----------------
__global__ __launch_bounds__(256) void oproj_kernel(const float* __restrict__ O,
        const float* __restrict__ Wout, const float* __restrict__ bout,
        float* __restrict__ y) {
    int g = blockIdx.x * 256 + threadIdx.x;
    int b = g >> 11, l = g & 2047;
    float orow[E];
    const float* src = O + ((size_t)b * Lsz + l) * E;
    #pragma unroll
    for (int e = 0; e < E; e += 4) {
        f32x4 t = *(const f32x4*)(src + e);
        orow[e] = t[0]; orow[e + 1] = t[1]; orow[e + 2] = t[2]; orow[e + 3] = t[3];
    }
    #pragma unroll
    for (int c = 0; c < E; ++c) {
        float acc = bout[c];
        #pragma unroll
        for (int e = 0; e < E; ++e) acc += orow[e] * Wout[c * E + e];
        y[((size_t)b * E + c) * Lsz + l] = acc;
    }
}

extern "C" void kernel_launch(void* const* d_in, const int* in_sizes, int n_in,
                              void* d_out, int out_size, void* d_ws, size_t ws_size,
                              hipStream_t stream) {
    const float* x    = (const float*)d_in[0];
    const float* Wqkv = (const float*)d_in[1];
    const float* bqkv = (const float*)d_in[2];
    const float* Wout = (const float*)d_in[3];
    const float* bout = (const float*)d_in[4];
    float* y = (float*)d_out;

    char* ws = (char*)d_ws;
    const size_t szQ = (size_t)Bsz * Lsz * E * sizeof(u16);   // 8.39 MB
    const size_t szM = (size_t)Lsz * Lsz * sizeof(u16);       // 8.39 MB
    u16* Q   = (u16*)(ws);
    u16* K   = (u16*)(ws + szQ);
    u16* Vc  = (u16*)(ws + 2 * szQ);
    u16* M   = (u16*)(ws + 3 * szQ);
    float* O = (float*)(ws + 3 * szQ + szM);                  // 16.78 MB f32

    hipLaunchKernelGGL(mask_kernel, dim3((Lsz * Lsz) / 256), dim3(256), 0, stream, M);
    hipLaunchKernelGGL(qkv_kernel, dim3((Bsz * Lsz) / 256), dim3(256), 0, stream,
                       x, Wqkv, bqkv, Q, K, Vc);
    hipLaunchKernelGGL(attn_kernel, dim3(Bsz * (Lsz / 128)), dim3(256), 32768, stream,
                       Q, K, Vc, M, O);
    hipLaunchKernelGGL(oproj_kernel, dim3((Bsz * Lsz) / 256), dim3(256), 0, stream,
                       O, Wout, bout, y);
}

// Round 11
// 193.831 us; speedup vs baseline: 1.0474x; 1.0021x over previous
//
#include <hip/hip_runtime.h>
#include <cstdint>
#include <cstddef>

#define E 32
#define Bsz 64
#define Lsz 2048
#define JCHUNK 128
#define NCH (Lsz / JCHUNK)   // 16

typedef float f32x4 __attribute__((ext_vector_type(4)));
typedef __bf16 bf16x8 __attribute__((ext_vector_type(8)));
typedef __bf16 bf16x4 __attribute__((ext_vector_type(4)));
typedef short s16x8 __attribute__((ext_vector_type(8)));
typedef short s16x4 __attribute__((ext_vector_type(4)));
typedef unsigned short u16;

typedef __attribute__((address_space(3))) unsigned int as3_u32;
typedef __attribute__((address_space(1))) const unsigned int as1_u32;

__device__ inline u16 f2bf(float f) {
    union { float f; unsigned u; } x; x.f = f;
    unsigned r = x.u + 0x7FFFu + ((x.u >> 16) & 1u);
    return (u16)(r >> 16);
}

__device__ inline float fexp2(float x) {
#if __has_builtin(__builtin_amdgcn_exp2f)
    return __builtin_amdgcn_exp2f(x);   // raw v_exp_f32
#else
    return exp2f(x);
#endif
}

// async global -> LDS, 16 B per lane; LDS dst must be wave-uniform (HW adds lane*16)
__device__ inline void glds(const void* g, void* l) {
    __builtin_amdgcn_global_load_lds((as1_u32*)g, (as3_u32*)l, 16, 0, 0);
}

// hardware transpose read (validated v5-v7): 16x16 bf16 subtile -> PV B-fragment
#define TRR(dst, areg, imm) \
    asm volatile("ds_read_b64_tr_b16 %0, %1 offset:" #imm : "=v"(dst) : "v"(areg))

// PV mfma: D = A(16x16) * B(16x16) + C
__device__ inline f32x4 pv_mfma(bf16x4 a, bf16x4 b, f32x4 c) {
#if __has_builtin(__builtin_amdgcn_mfma_f32_16x16x16_bf16)
    return __builtin_amdgcn_mfma_f32_16x16x16_bf16(a, b, c, 0, 0, 0);
#elif __has_builtin(__builtin_amdgcn_mfma_f32_16x16x16bf16_1k)
    return __builtin_amdgcn_mfma_f32_16x16x16bf16_1k(
        __builtin_bit_cast(s16x4, a), __builtin_bit_cast(s16x4, b), c, 0, 0, 0);
#else
    asm volatile("s_nop 1\n\t"
                 "v_mfma_f32_16x16x16_bf16 %0, %1, %2, %0\n\t"
                 "s_nop 3"
                 : "+v"(c) : "v"(a), "v"(b));
    return c;
#endif
}

// ---------------- Full PSF mask: M[i][j] = bilinear(i,j) / sqrt(E) * log2(e), bf16 ----------------
__global__ __launch_bounds__(256) void mask_kernel(u16* __restrict__ M) {
    int g = blockIdx.x * 256 + threadIdx.x;
    int i = g >> 11, j = g & 2047;
    const float scale = 21.0f / 2048.0f;
    float si = fmaxf((i + 0.5f) * scale - 0.5f, 0.f);
    float sj = fmaxf((j + 0.5f) * scale - 0.5f, 0.f);
    int i0 = (int)si; float fi = si - (float)i0;
    int j0 = (int)sj; float fj = sj - (float)j0;
    int i0c = min(i0, 20), i1c = min(i0 + 1, 20);
    int j0c = min(j0, 20), j1c = min(j0 + 1, 20);
    int d00 = abs(i0c - j0c), d01 = abs(i0c - j1c), d10 = abs(i1c - j0c), d11 = abs(i1c - j1c);
    float t00 = __expf(-0.125f * (float)(d00 * d00));
    float t01 = __expf(-0.125f * (float)(d01 * d01));
    float t10 = __expf(-0.125f * (float)(d10 * d10));
    float t11 = __expf(-0.125f * (float)(d11 * d11));
    float m = (1.f - fi) * ((1.f - fj) * t00 + fj * t01)
            + fi * ((1.f - fj) * t10 + fj * t11);
    // * 1/sqrt(32) * log2(e) / Z, folded at compile time (Z = sum exp(-x^2/8), x=-10..10)
    m = m * (0.17677669529663687f * 1.4426950408889634f / 5.0132563952f);
    M[g] = f2bf(m);
}

// ---------------- QKV: x[B][E][L] f32 -> Q,K [B][L][E] bf16; V chunked tr-layout ----------------
// Vc[b][jc=l>>7][eh=e>>4][j=l&127][e&15]  (8-KB chunks = attn's LDS image)
__global__ __launch_bounds__(256) void qkv_kernel(const float* __restrict__ x,
        const float* __restrict__ Wqkv, const float* __restrict__ bqkv,
        u16* __restrict__ Q, u16* __restrict__ K, u16* __restrict__ Vc) {
    int g = blockIdx.x * 256 + threadIdx.x;
    int b = g >> 11, l = g & 2047;
    float xr[E];
    #pragma unroll
    for (int c = 0; c < E; ++c) xr[c] = x[((size_t)b * E + c) * Lsz + l];

    #pragma unroll
    for (int part = 0; part < 2; ++part) {
        u16* dst = (part == 0) ? Q : K;
        s16x8 pk[4];
        #pragma unroll
        for (int e = 0; e < E; ++e) {
            int o = part * E + e;
            float acc = bqkv[o];
            #pragma unroll
            for (int c = 0; c < E; ++c) acc += xr[c] * Wqkv[o * E + c];
            pk[e >> 3][e & 7] = (short)f2bf(acc);
        }
        s16x8* dp = (s16x8*)(dst + ((size_t)b * Lsz + l) * E);
        #pragma unroll
        for (int q8 = 0; q8 < 4; ++q8) dp[q8] = pk[q8];
    }
    s16x8 pv[4];
    #pragma unroll
    for (int e = 0; e < E; ++e) {
        int o = 2 * E + e;
        float acc = bqkv[o];
        #pragma unroll
        for (int c = 0; c < E; ++c) acc += xr[c] * Wqkv[o * E + c];
        pv[e >> 3][e & 7] = (short)f2bf(acc);
    }
    u16* vd = Vc + ((size_t)b * 16 + (l >> 7)) * 4096 + (size_t)(l & 127) * 16;
    *(s16x8*)(vd)            = pv[0];   // eh=0, e 0..7
    *(s16x8*)(vd + 8)        = pv[1];   // eh=0, e 8..15
    *(s16x8*)(vd + 2048)     = pv[2];   // eh=1, e 16..23
    *(s16x8*)(vd + 2048 + 8) = pv[3];   // eh=1, e 24..31
}

// ---------------- Flash attention v8: 8 waves x 16 q-rows, 100% occupancy target ----------------
// 1024 blocks (B x L/128) x 512 threads. 4 blocks/CU x 8 waves = 32 waves/CU.
// LDS 32 KB dynamic: K[2][128][32]h swizzled at byte 0; V[2][2][128][16]h at 16384.
// Per-lane dsum denominator (v4-verified reduce) instead of ones-MFMA: saves VGPR+MFMA.
__global__ __launch_bounds__(512, 8) void attn_kernel(const u16* __restrict__ Q,
        const u16* __restrict__ Kg, const u16* __restrict__ Vc,
        const u16* __restrict__ M, float* __restrict__ O) {
    extern __shared__ char smem[];
    int blk = blockIdx.x;
    int b = blk >> 4;
    int qblk = blk & 15;
    int tid = threadIdx.x;
    int wave = tid >> 6, lane = tid & 63;
    int lrow = lane & 15, kgrp = lane >> 4;
    int qbase = qblk * 128 + wave * 16;

    const size_t bLE = (size_t)b * Lsz * E;
    bf16x8 qf = *(const bf16x8*)(Q + bLE + (size_t)(qbase + lrow) * E + kgrp * 8);
    const u16* mp0 = M + (size_t)(qbase + lrow) * Lsz + kgrp * 4;

    // staging: K image LDS[row][slot] = K[row][slot ^ (row&3)] (16B slots); V linear
    const char* kcbase = (const char*)(Kg + bLE);
    const char* vcbase = (const char*)(Vc + bLE);
    int row = tid >> 2, s4 = tid & 3;
    int ksrc = row * 64 + ((s4 ^ (row & 3)) << 4);
    int vsrc = tid * 16;
    u16* smem_h = (u16*)smem;
    int kslot = (kgrp ^ (lrow & 3)) * 8;          // swizzled read slot (halfs)
    unsigned vbase = (unsigned)(uintptr_t)(__attribute__((address_space(3))) u16*)(smem_h + 8192)
                   + (unsigned)(lane * 8);

#define STAGE(bufn, jc_) do { \
    glds(kcbase + (size_t)(jc_) * 8192 + ksrc, smem + (bufn) * 8192 + wave * 1024); \
    glds(vcbase + (size_t)(jc_) * 8192 + vsrc, smem + 16384 + (bufn) * 8192 + wave * 1024); \
} while (0)

    f32x4 o00 = {0,0,0,0}, o01 = {0,0,0,0};
    float dsum = 0.f;

#define JT(jt, vr0, vr1) do { \
    bf16x8 kf = *(const bf16x8*)(smem_h + buf * 4096 + ((jt) * 16 + lrow) * 32 + kslot); \
    f32x4 zc = {0,0,0,0}; \
    f32x4 s0 = __builtin_amdgcn_mfma_f32_16x16x32_bf16(kf, qf, zc, 0, 0, 0); \
    bf16x4 mm0 = *(const bf16x4*)(mp0 + jco + (jt) * 16); \
    bf16x4 pa0; \
    _Pragma("unroll") for (int r = 0; r < 4; ++r) { \
        float p = fexp2(s0[r] * (float)mm0[r]); \
        dsum += p; pa0[r] = (__bf16)p; \
    } \
    bf16x4 vf0 = __builtin_bit_cast(bf16x4, vr0); \
    bf16x4 vf1 = __builtin_bit_cast(bf16x4, vr1); \
    o00 = pv_mfma(pa0, vf0, o00); \
    o01 = pv_mfma(pa0, vf1, o01); \
} while (0)

// one pair of j-tiles: 4 TRR (2 per JT), wait, then 2 JTs — caps TRR liveness at 8 VGPR
#define JPAIR(jta, jtb, offa0, offa1, offb0, offb1) do { \
    s16x4 ta0, ta1, tb0, tb1; \
    TRR(ta0, av, offa0); TRR(ta1, av, offa1); \
    TRR(tb0, av, offb0); TRR(tb1, av, offb1); \
    asm volatile("s_waitcnt lgkmcnt(0)" ::: "memory"); \
    __builtin_amdgcn_sched_barrier(0); \
    JT(jta, ta0, ta1); \
    JT(jtb, tb0, tb1); \
} while (0)

    int buf = 0;
    STAGE(0, 0);
    __syncthreads();
    #pragma unroll 1
    for (int jc = 0; jc < NCH; ++jc) {
        if (jc + 1 < NCH) STAGE(buf ^ 1, jc + 1);   // next chunk into other buffer
        const int jco = jc * JCHUNK;
        unsigned av = vbase + (buf ? 8192u : 0u);
        __builtin_amdgcn_s_setprio(1);
        JPAIR(0, 1, 0, 4096, 512, 4608);
        JPAIR(2, 3, 1024, 5120, 1536, 5632);
        JPAIR(4, 5, 2048, 6144, 2560, 6656);
        JPAIR(6, 7, 3072, 7168, 3584, 7680);
        __builtin_amdgcn_s_setprio(0);
        __syncthreads();   // stage loads landed during compute; drain is cheap
        buf ^= 1;
    }
#undef JPAIR
#undef JT
#undef STAGE

    // denominator: per-lane partial for q=lrow over this lane's j-slots; full-row reduce
    dsum += __shfl_xor(dsum, 16);
    dsum += __shfl_xor(dsum, 32);
    // PV output C-layout: lane holds rows q = kgrp*4+r, cols e = lrow / 16+lrow
    #pragma unroll
    for (int r = 0; r < 4; ++r) {
        float inv = 1.0f / __shfl(dsum, kgrp * 4 + r);
        size_t rq = (size_t)(qbase + kgrp * 4 + r);
        O[bLE + rq * E + lrow]      = o00[r] * inv;
        O[bLE + rq * E + 16 + lrow] = o01[r] * inv;
    }
}

// ---------------- Output projection: O[B][L][E] f32 -> y[B][E][L] f32 ----------------
__global__ __launch_bounds__(256) void oproj_kernel(const float* __restrict__ O,
        const float* __restrict__ Wout, const float* __restrict__ bout,
        float* __restrict__ y) {
    int g = blockIdx.x * 256 + threadIdx.x;
    int b = g >> 11, l = g & 2047;
    float orow[E];
    const float* src = O + ((size_t)b * Lsz + l) * E;
    #pragma unroll
    for (int e = 0; e < E; e += 4) {
        f32x4 t = *(const f32x4*)(src + e);
        orow[e] = t[0]; orow[e + 1] = t[1]; orow[e + 2] = t[2]; orow[e + 3] = t[3];
    }
    #pragma unroll
    for (int c = 0; c < E; ++c) {
        float acc = bout[c];
        #pragma unroll
        for (int e = 0; e < E; ++e) acc += orow[e] * Wout[c * E + e];
        y[((size_t)b * E + c) * Lsz + l] = acc;
    }
}

extern "C" void kernel_launch(void* const* d_in, const int* in_sizes, int n_in,
                              void* d_out, int out_size, void* d_ws, size_t ws_size,
                              hipStream_t stream) {
    const float* x    = (const float*)d_in[0];
    const float* Wqkv = (const float*)d_in[1];
    const float* bqkv = (const float*)d_in[2];
    const float* Wout = (const float*)d_in[3];
    const float* bout = (const float*)d_in[4];
    float* y = (float*)d_out;

    char* ws = (char*)d_ws;
    const size_t szQ = (size_t)Bsz * Lsz * E * sizeof(u16);   // 8.39 MB
    const size_t szM = (size_t)Lsz * Lsz * sizeof(u16);       // 8.39 MB
    u16* Q   = (u16*)(ws);
    u16* K   = (u16*)(ws + szQ);
    u16* Vc  = (u16*)(ws + 2 * szQ);
    u16* M   = (u16*)(ws + 3 * szQ);
    float* O = (float*)(ws + 3 * szQ + szM);                  // 16.78 MB f32

    hipLaunchKernelGGL(mask_kernel, dim3((Lsz * Lsz) / 256), dim3(256), 0, stream, M);
    hipLaunchKernelGGL(qkv_kernel, dim3((Bsz * Lsz) / 256), dim3(256), 0, stream,
                       x, Wqkv, bqkv, Q, K, Vc);
    hipLaunchKernelGGL(attn_kernel, dim3(Bsz * (Lsz / 128)), dim3(512), 32768, stream,
                       Q, K, Vc, M, O);
    hipLaunchKernelGGL(oproj_kernel, dim3((Bsz * Lsz) / 256), dim3(256), 0, stream,
                       O, Wout, bout, y);
}